// Round 5
// baseline (394.757 us; speedup 1.0000x reference)
//
#include <hip/hip_runtime.h>
#include <hip/hip_bf16.h>
#include <math.h>

// Problem constants (from reference)
#define B_ROWS 4096
#define C_ROWS 2048
#define D_DIM  2048
#define NUM 2
#define MAX_ITER 15
#define NEAREST 3
#define MARGIN 1.0f

typedef __bf16 bf16_t;
typedef bf16_t bf16x8 __attribute__((ext_vector_type(8)));
typedef float f32x4 __attribute__((ext_vector_type(4)));
typedef float f32x16 __attribute__((ext_vector_type(16)));
typedef int i32x4 __attribute__((ext_vector_type(4)));
typedef int i32x8 __attribute__((ext_vector_type(8)));   // 32 fp8 bytes = scaled-MFMA fragment
typedef unsigned char u8;

// ---------------------------------------------------------------------------
// MEASURED LEDGER (do not revisit):
//  R14 2-barrier 128^2 fp8-MX GEMM: 37.7us | R2 8-phase 256^2 @1blk/CU: 45.0us
//  (MfmaUtil 20%, lockstep) | R3 counted-vmcnt triple-buffer: 38.6us (null vs
//  drain -> stage latency not the bound) | R4 B-from-global: 64.3us (32 lines
//  per wave-instr gather kills the TA; operand redistribution MUST go via LDS)
//  | R1 cooperative grid.sync: ~95us PER SYNC on 768 blocks.
//  Intensity-87 variants blocked: acc=128 f32 -> <=2 waves/SIMD (VGPR);
//  256-tiles -> 384 blocks = 1.5 blk/CU (shape).
// THIS ROUND: single 768-block dispatch, conv -> gemm -> select gated by
// device-scope flags (no grid.sync). 3 blk/CU co-residency GUARANTEED by
// __launch_bounds__(256,3) + 48KB LDS + grid==768 -> spins deadlock-free
// (every block converts unconditionally before any wait).
// ---------------------------------------------------------------------------

// conv body: one wave converts one row (f32 -> fp8 e4m3 + exact f32 sumsq).
__device__ __forceinline__ void conv_row(int row,
                                         const float* __restrict__ F,
                                         const float* __restrict__ Cn,
                                         u8* __restrict__ Fq, u8* __restrict__ Cq,
                                         float* __restrict__ f2, float* __restrict__ c2,
                                         int lane) {
    const float* p; u8* q; float* sq; int r;
    if (row < B_ROWS) {
        r = row; p = F + (size_t)r * D_DIM; q = Fq + (size_t)r * D_DIM; sq = f2;
    } else {
        r = row - B_ROWS; p = Cn + (size_t)r * D_DIM; q = Cq + (size_t)r * D_DIM; sq = c2;
    }
    float s = 0.0f;
    #pragma unroll
    for (int it = 0; it < 4; ++it) {
        int k = (it * 64 + lane) * 8;
        float4 v0 = *(const float4*)(p + k);
        float4 v1 = *(const float4*)(p + k + 4);
        s += v0.x * v0.x + v0.y * v0.y + v0.z * v0.z + v0.w * v0.w;
        s += v1.x * v1.x + v1.y * v1.y + v1.z * v1.z + v1.w * v1.w;
        int lo = __builtin_amdgcn_cvt_pk_fp8_f32(v0.x, v0.y, 0, 0);
        lo     = __builtin_amdgcn_cvt_pk_fp8_f32(v0.z, v0.w, lo, 1);
        int hi = __builtin_amdgcn_cvt_pk_fp8_f32(v1.x, v1.y, 0, 0);
        hi     = __builtin_amdgcn_cvt_pk_fp8_f32(v1.z, v1.w, hi, 1);
        int2 st; st.x = lo; st.y = hi;
        *(int2*)(q + k) = st;
    }
    #pragma unroll
    for (int off = 32; off >= 1; off >>= 1) s += __shfl_down(s, off);
    if (lane == 0) sq[r] = s;
}

// select body: one wave, one feature row. Iterative argmin w/ exclusion over
// Dfc row; on-demand trust from Dcc via lexicographic rank count (stable-
// argsort equivalence). Returns hinge (valid lane 0).
__device__ __forceinline__ float select_row(int b,
                                            const bf16_t* __restrict__ Dfc,
                                            const bf16_t* __restrict__ Dcc,
                                            int lane) {
    int label = b / NUM;
    const bf16_t* row = Dfc + (size_t)b * C_ROWS;

    float vals[32];
    #pragma unroll
    for (int g = 0; g < 4; ++g) {
        bf16x8 v = *(const bf16x8*)(row + g * 512 + lane * 8);
        #pragma unroll
        for (int e = 0; e < 8; ++e) {
            int n = g * 512 + lane * 8 + e;
            float f = (float)v[e];
            vals[g * 8 + e] = (n == label) ? INFINITY : f;
        }
    }

    unsigned int excl = 0;
    float min_diff = 0.0f;
    int found = 0;
    for (int it = 0; it < MAX_ITER; ++it) {
        float bestv = INFINITY; int bestidx = 0x7fffffff;
        #pragma unroll
        for (int g = 0; g < 4; ++g)
            #pragma unroll
            for (int e = 0; e < 8; ++e) {
                int bit = g * 8 + e;
                if (excl & (1u << bit)) continue;
                float v = vals[bit];
                int idx = g * 512 + lane * 8 + e;
                if (v < bestv || (v == bestv && idx < bestidx)) { bestv = v; bestidx = idx; }
            }
        for (int off = 32; off >= 1; off >>= 1) {
            float ov = __shfl_down(bestv, off); int oi = __shfl_down(bestidx, off);
            if (ov < bestv || (ov == bestv && oi < bestidx)) { bestv = ov; bestidx = oi; }
        }
        int sel = __shfl(bestidx, 0);
        float selv = __shfl(bestv, 0);

        const bf16_t* crow = Dcc + (size_t)sel * C_ROWS;
        float dl = (float)crow[label];
        int cnt = 0;
        #pragma unroll
        for (int g = 0; g < 4; ++g) {
            bf16x8 v = *(const bf16x8*)(crow + g * 512 + lane * 8);
            #pragma unroll
            for (int e = 0; e < 8; ++e) {
                int idx = g * 512 + lane * 8 + e;
                float f = (float)v[e];
                cnt += (f < dl || (f == dl && idx < label)) ? 1 : 0;
            }
        }
        #pragma unroll
        for (int off = 32; off >= 1; off >>= 1) cnt += __shfl_down(cnt, off);
        cnt = __shfl(cnt, 0);
        bool trusted = (cnt >= NEAREST);

        if (trusted) { min_diff = sqrtf(fmaxf(selv, 0.0f)); found = 1; break; }
        if (((sel >> 3) & 63) == lane) excl |= 1u << (((sel >> 9) << 3) | (sel & 7));
    }
    float same = sqrtf(fmaxf((float)row[label], 0.0f));
    float md = found ? min_diff : 0.0f;
    return fmaxf(MARGIN + same - md, 0.0f);
}

// ---------------------------------------------------------------------------
// fused_pipeline: conv | flags | gemm (R3-p3 inner loop, verified) | counters
// | select.  Grid = 768 x 256 exactly (3 blk/CU co-resident).
//
// Flag protocol (all cross-block edges release/acquire, G16):
//  - block raw converts rows [8*raw, 8*raw+8) (centers-first index space:
//    cr<2048 -> center cr, else feature cr-2048). Release: per-wave
//    vmcnt(0) drain -> __syncthreads -> tid0 __threadfence + flags[raw]=1.
//  - gemm tile (bx,by) acquires the 32 flags covering its A panel (16) and
//    B panel (16), then runs the UNCHANGED R3 pipeline (minus setprio,
//    m190: hurts pre-8-phase GEMM).
//  - tile->block map: XCD x (= raw&7, HW round-robin) runs its 2 Dcc
//    panels FIRST (by = 32+2x, 33+2x), then 4 Dfc panels (by = 4x..4x+3)
//    -> dccCnt==256 lands ~1/3 into gemm so select overlaps the tail;
//    contiguous by per XCD preserves A-panel L2 locality (T1).
//  - after tile store: per-wave vmcnt drain -> __syncthreads -> tid0
//    __threadfence + atomicAdd(fcCnt[by] | dccCnt).
//  - select wave gw=raw*4+wave handles row gw (and 3072+gw if gw<1024);
//    spins on fcCnt[row>>7]==16 && dccCnt==256, acquire fence, runs.
// GEMM PITFALLS (measured, keep): R5 128B-row banking w/o swizzle; R7
// nonzero imm offset on global_load_lds; R11 per-lane ROW scatter; R13
// unswizzled rows; R4 B-from-global gather.
// ---------------------------------------------------------------------------
__global__ __launch_bounds__(256, 3) void fused_pipeline(
        const float* __restrict__ F, const float* __restrict__ Cn,
        u8* __restrict__ Fq, u8* __restrict__ Cq,
        float* __restrict__ f2, float* __restrict__ c2,
        bf16_t* __restrict__ Dfc, bf16_t* __restrict__ Dcc,
        float* __restrict__ out, int* __restrict__ sync) {
    __shared__ __align__(16) u8 As[3][128 * 64];   // 24 KiB
    __shared__ __align__(16) u8 Bs[3][128 * 64];   // 24 KiB
    __shared__ float hs[4];

    const int raw  = blockIdx.x;
    const int tid  = threadIdx.x;
    const int wave = tid >> 6;
    const int lane = tid & 63;

    int* flags  = sync;          // [768] conv row-group flags
    int* fcCnt  = sync + 768;    // [32]  Dfc panel completion counters
    int* dccCnt = sync + 800;    // [1]   Dcc tile completion counter

    // ================= phase 1: conv (8 rows per block) =================
    if (raw == 0 && tid == 0) out[0] = 0.0f;   // ordered before our release
    #pragma unroll
    for (int j = 0; j < 2; ++j) {
        int cr  = raw * 8 + wave * 2 + j;              // centers-first order
        int row = (cr < C_ROWS) ? (B_ROWS + cr) : (cr - C_ROWS);
        conv_row(row, F, Cn, Fq, Cq, f2, c2, lane);
    }
    asm volatile("s_waitcnt vmcnt(0)" ::: "memory");   // drain THIS wave's stores
    __syncthreads();
    if (tid == 0) {
        __threadfence();                               // agent release (wb L2)
        __hip_atomic_store(&flags[raw], 1, __ATOMIC_RELAXED, __HIP_MEMORY_SCOPE_AGENT);
    }

    // ================= phase 2: gemm tile =================
    // tile map: x = raw&7 (XCD), t = raw>>3 in [0,96)
    const int x = raw & 7;
    const int t = raw >> 3;
    int bx, by;
    if (t < 32) { by = 32 + 2 * x + (t >> 4); bx = t & 15; }        // Dcc first
    else        { int tt = t - 32; by = 4 * x + (tt >> 4); bx = tt & 15; }

    const u8* A; const float* a2v; bf16_t* Out; int bm, aFlagBase;
    if (by < B_ROWS / 128) {
        A = Fq; a2v = f2; Out = Dfc; bm = by * 128; aFlagBase = 256 + bm / 8;
    } else {
        A = Cq; a2v = c2; Out = Dcc; bm = (by - B_ROWS / 128) * 128; aFlagBase = bm / 8;
    }
    const int bn = bx * 128;
    const int bFlagBase = bn / 8;
    const int N = C_ROWS, K = D_DIM;

    // acquire the 32 producer flags (per wave; BARs below resync the block)
    for (;;) {
        int ok = 1;
        if (lane < 32) {
            int fi = (lane < 16) ? (aFlagBase + lane) : (bFlagBase + lane - 16);
            ok = __hip_atomic_load(&flags[fi], __ATOMIC_RELAXED, __HIP_MEMORY_SCOPE_AGENT);
        }
        if (__all(ok != 0)) break;
        __builtin_amdgcn_s_sleep(16);
    }
    __threadfence();                                   // acquire (inv L1/L2)

    const int wmL = (wave >> 1) * 64;
    const int wnL = (wave & 1) * 64;
    const int kbyt  = ((lane & 3) ^ ((lane >> 3) & 3)) * 16;
    const int wbase = wave * 1024;
    const u8* gA = A  + (size_t)(bm + wave * 16 + (lane >> 2)) * K + kbyt;
    const u8* gB = Cq + (size_t)(bn + wave * 16 + (lane >> 2)) * K + kbyt;

    const int m31 = lane & 31;
    const int h   = lane >> 5;
    const int swr = (m31 >> 1) & 3;
    const int sl0 = ((h * 2    ) ^ swr) * 16;
    const int sl1 = ((h * 2 + 1) ^ swr) * 16;

    f32x16 acc[2][2] = {};

#define GLD(dst, src)                                                          \
    __builtin_amdgcn_global_load_lds(                                          \
        (const __attribute__((address_space(1))) void*)(src),                  \
        (__attribute__((address_space(3))) void*)(dst), 16, 0, 0)
#define STAGE(q, p)                                                            \
    do {                                                                       \
        GLD(&As[q][0 * 4096 + wbase], gA + (size_t)0 * 64 * K + (p) * 64);     \
        GLD(&As[q][1 * 4096 + wbase], gA + (size_t)1 * 64 * K + (p) * 64);     \
        GLD(&Bs[q][0 * 4096 + wbase], gB + (size_t)0 * 64 * K + (p) * 64);     \
        GLD(&Bs[q][1 * 4096 + wbase], gB + (size_t)1 * 64 * K + (p) * 64);     \
    } while (0)

    auto rd = [&](const u8* buf, int rowbase) -> i32x8 {
        const u8* pp = buf + rowbase * 64;
        i32x4 lo = *(const i32x4*)(pp + sl0);
        i32x4 hi = *(const i32x4*)(pp + sl1);
        i32x8 r;
        r[0] = lo.x; r[1] = lo.y; r[2] = lo.z; r[3] = lo.w;
        r[4] = hi.x; r[5] = hi.y; r[6] = hi.z; r[7] = hi.w;
        return r;
    };

#define PANEL(q)                                                               \
    do {                                                                       \
        i32x8 a0 = rd(As[q], wmL + m31);                                       \
        i32x8 a1 = rd(As[q], wmL + 32 + m31);                                  \
        i32x8 b0 = rd(Bs[q], wnL + m31);                                       \
        i32x8 b1 = rd(Bs[q], wnL + 32 + m31);                                  \
        acc[0][0] = __builtin_amdgcn_mfma_scale_f32_32x32x64_f8f6f4(           \
            a0, b0, acc[0][0], 0, 0, 0, 0x7F7F7F7F, 0, 0x7F7F7F7F);            \
        acc[0][1] = __builtin_amdgcn_mfma_scale_f32_32x32x64_f8f6f4(           \
            a0, b1, acc[0][1], 0, 0, 0, 0x7F7F7F7F, 0, 0x7F7F7F7F);            \
        acc[1][0] = __builtin_amdgcn_mfma_scale_f32_32x32x64_f8f6f4(           \
            a1, b0, acc[1][0], 0, 0, 0, 0x7F7F7F7F, 0, 0x7F7F7F7F);            \
        acc[1][1] = __builtin_amdgcn_mfma_scale_f32_32x32x64_f8f6f4(           \
            a1, b1, acc[1][1], 0, 0, 0, 0x7F7F7F7F, 0, 0x7F7F7F7F);            \
    } while (0)
#define BAR() __builtin_amdgcn_s_barrier()
#define WAITV(n) asm volatile("s_waitcnt vmcnt(" #n ")" ::: "memory")

    // prologue: panels 0,1 in flight; land 0; collective barrier
    STAGE(0, 0);
    STAGE(1, 1);
    WAITV(4);
    BAR();

    #pragma unroll 1
    for (int pb = 0; pb < 30; pb += 3) {
        STAGE(2, pb + 2);
        PANEL(0);
        WAITV(4);
        BAR();
        STAGE(0, pb + 3);
        PANEL(1);
        WAITV(4);
        BAR();
        STAGE(1, pb + 4);
        PANEL(2);
        WAITV(4);
        BAR();
    }
    PANEL(0);            // panel 30
    WAITV(0);            // drain panel 31
    BAR();
    PANEL(1);            // panel 31

    // epilogue: d2 = a2[m] + c2[n] - 2*dot, stored bf16.
    // 32x32 C/D (m74/m101): col = lane&31, row = (reg&3)+8*(reg>>2)+4*(lane>>5)
    #pragma unroll
    for (int i = 0; i < 2; ++i) {
        #pragma unroll
        for (int r = 0; r < 16; ++r) {
            int m = bm + wmL + i * 32 + (r & 3) + 8 * (r >> 2) + 4 * h;
            float am = a2v[m];
            #pragma unroll
            for (int j = 0; j < 2; ++j) {
                int n = bn + wnL + j * 32 + m31;
                Out[(size_t)m * N + n] = (bf16_t)(am + c2[n] - 2.0f * acc[i][j][r]);
            }
        }
    }
#undef GLD
#undef STAGE
#undef PANEL
#undef BAR
#undef WAITV

    // release this tile's completion
    asm volatile("s_waitcnt vmcnt(0)" ::: "memory");
    __syncthreads();
    if (tid == 0) {
        __threadfence();
        if (by < 32) atomicAdd(&fcCnt[by], 1);
        else         atomicAdd(dccCnt, 1);
    }

    // ================= phase 3: select (overlaps gemm tail) =================
    float hsum = 0.0f;
    const int gw = raw * 4 + wave;
    #pragma unroll 1
    for (int rep = 0; rep < 2; ++rep) {
        int b = (rep == 0) ? gw : (3072 + gw);
        if (rep == 1 && gw >= 1024) break;
        int pnl = b >> 7;
        while (__hip_atomic_load(&fcCnt[pnl], __ATOMIC_RELAXED, __HIP_MEMORY_SCOPE_AGENT) < 16 ||
               __hip_atomic_load(dccCnt,     __ATOMIC_RELAXED, __HIP_MEMORY_SCOPE_AGENT) < 256)
            __builtin_amdgcn_s_sleep(32);
        __threadfence();                              // acquire
        hsum += select_row(b, Dfc, Dcc, lane);
    }
    if (lane == 0) hs[wave] = hsum;
    __syncthreads();
    if (tid == 0)
        atomicAdd(out, (hs[0] + hs[1] + hs[2] + hs[3]) * (1.0f / (float)B_ROWS));
}

// ---------------------------------------------------------------------------
extern "C" void kernel_launch(void* const* d_in, const int* in_sizes, int n_in,
                              void* d_out, int out_size, void* d_ws, size_t ws_size,
                              hipStream_t stream) {
    const float* feature = (const float*)d_in[0];  // 4096 x 2048
    const float* centers = (const float*)d_in[1];  // 2048 x 2048
    float* out = (float*)d_out;                    // scalar

    // Workspace layout
    bf16_t* Dfc  = (bf16_t*)d_ws;                            // 4096*2048 bf16
    bf16_t* Dcc  = Dfc + (size_t)B_ROWS * C_ROWS;            // 2048*2048 bf16
    u8*     Fq   = (u8*)(Dcc + (size_t)C_ROWS * C_ROWS);     // 4096*2048 fp8
    u8*     Cq   = Fq + (size_t)B_ROWS * D_DIM;              // 2048*2048 fp8
    float*  f2   = (float*)(Cq + (size_t)C_ROWS * D_DIM);    // 4096
    float*  c2   = f2 + B_ROWS;                              // 2048
    int*    sync = (int*)(c2 + C_ROWS);                      // 768+32+1 ints

    // Flags must start at 0 (ws is poisoned every iteration). Capture-legal.
    hipMemsetAsync(sync, 0, 4096, stream);

    fused_pipeline<<<768, 256, 0, stream>>>(feature, centers, Fq, Cq,
                                            f2, c2, Dfc, Dcc, out, sync);
}

// Round 7
// 133.706 us; speedup vs baseline: 2.9524x; 2.9524x over previous
//
#include <hip/hip_runtime.h>
#include <hip/hip_bf16.h>
#include <math.h>

// Problem constants (from reference)
#define B_ROWS 4096
#define C_ROWS 2048
#define D_DIM  2048
#define NUM 2
#define MAX_ITER 15
#define NEAREST 3
#define MARGIN 1.0f

typedef __bf16 bf16_t;
typedef bf16_t bf16x8 __attribute__((ext_vector_type(8)));
typedef float f32x4 __attribute__((ext_vector_type(4)));
typedef int i32x4 __attribute__((ext_vector_type(4)));
typedef int i32x8 __attribute__((ext_vector_type(8)));   // 32 fp8 bytes = scaled-MFMA fragment
typedef unsigned char u8;

// ---------------------------------------------------------------------------
// MEASURED LEDGER (do not revisit):
//  GEMM: R14 2-barrier 16x16x128 @128^2/3blk = 37.7us BEST | R3 counted-vmcnt
//  triple-buffer 32x32x64 = 38.6 (null vs drain -> stage latency not bound) |
//  R2 8-phase 256^2 @1blk/CU = 45.0 (lockstep, MfmaUtil 20%) | R4
//  B-from-global = 64.3 (32 lines/wave-instr gather kills TA; operand
//  redistribution MUST go via LDS).
//  FUSION: R1 cooperative grid.sync ~95us/sync | R5 flag-gated spin = +250us
//  idle (device-scope atomic polling serializes at the below-L2 coherence
//  point; poll storm convoys the producers). Cross-grid sync >> kernel
//  boundary cost on MI355X. THREE-KERNEL STREAM IS THE STRUCTURE.
//  Fixed harness overhead ~80us/iter (268MB poison fill + launch fixed).
// THIS ROUND (resubmit; R6 bench was a container failure, no data):
// R0 revert + XCD-contiguous GEMM tile remap (T1, bijective, 768%8==0):
// XCD x owns by-panels [6x,6x+6), bx-major -> A-panel fetched once per XCD
// instead of ~8x (FETCH 50MB -> ~32MB predicted).
// ---------------------------------------------------------------------------

// ---------------------------------------------------------------------------
// conv: one wave per row, f32 -> fp8 e4m3 (HW cvt_pk, OCP-native on gfx950)
// + row sumsq (exact, from f32) via shuffle. Verified R13/R14: absmax 0.0.
// Rows [0,4096) = feature, [4096,6144) = centers. 4 waves/block.
// Block 0 zero-inits out (select accumulates onto it; stream order).
// ---------------------------------------------------------------------------
__global__ __launch_bounds__(256) void conv_rows(const float* __restrict__ F,
                                                 const float* __restrict__ Cn,
                                                 u8* __restrict__ Fq,
                                                 u8* __restrict__ Cq,
                                                 float* __restrict__ f2,
                                                 float* __restrict__ c2,
                                                 float* __restrict__ out) {
    if (blockIdx.x == 0 && threadIdx.x == 0) out[0] = 0.0f;
    int wave = threadIdx.x >> 6;
    int lane = threadIdx.x & 63;
    int row = blockIdx.x * 4 + wave;          // 0..6143
    const float* p; u8* q; float* sq; int r;
    if (row < B_ROWS) {
        r = row; p = F + (size_t)r * D_DIM; q = Fq + (size_t)r * D_DIM; sq = f2;
    } else {
        r = row - B_ROWS; p = Cn + (size_t)r * D_DIM; q = Cq + (size_t)r * D_DIM; sq = c2;
    }
    float s = 0.0f;
    #pragma unroll
    for (int it = 0; it < 4; ++it) {
        int k = (it * 64 + lane) * 8;         // 8 consecutive floats per lane
        float4 v0 = *(const float4*)(p + k);
        float4 v1 = *(const float4*)(p + k + 4);
        s += v0.x * v0.x + v0.y * v0.y + v0.z * v0.z + v0.w * v0.w;
        s += v1.x * v1.x + v1.y * v1.y + v1.z * v1.z + v1.w * v1.w;
        int lo = __builtin_amdgcn_cvt_pk_fp8_f32(v0.x, v0.y, 0, 0);
        lo     = __builtin_amdgcn_cvt_pk_fp8_f32(v0.z, v0.w, lo, 1);
        int hi = __builtin_amdgcn_cvt_pk_fp8_f32(v1.x, v1.y, 0, 0);
        hi     = __builtin_amdgcn_cvt_pk_fp8_f32(v1.z, v1.w, hi, 1);
        int2 st; st.x = lo; st.y = hi;
        *(int2*)(q + k) = st;                 // 8 bytes, coalesced
    }
    #pragma unroll
    for (int off = 32; off >= 1; off >>= 1) s += __shfl_down(s, off);
    if (lane == 0) sq[r] = s;
}

// ---------------------------------------------------------------------------
// Fused fp8 distance GEMM, MX-SCALED K=128 MFMA (scale = 1.0 -> arithmetic
// identical to plain fp8; just 2x the per-instruction K depth at the
// f8f6f4 rate — m148: 1628 vs 995 TF on this structure).
// Layout (R14, measured 37.7us): BK=128 as two [128 rows][64 B] K-panels;
// XOR bank swizzle — 16B chunk c of row r lives at slot c ^ ((r>>1)&3);
// staging via global_load_lds keeps 4-lane/64B coalescing (the swizzle is a
// within-row lane permutation, NOT the R11 row-scatter).
// Fragment for mfma_scale_f32_16x16x128_f8f6f4: lane l holds 32 k-bytes,
// row = l&15, k-group kg = l>>4 -> panel kg>>1, 32B-half kg&1 -> two fixed
// ds_read_b128 from swizzled slots (2-way bank aliasing = free, m136).
// MEASURED PITFALLS (do not revisit): R5 128B-row banking; R7 nonzero imm
// offset on global_load_lds; R11 per-lane ROW scatter breaks coalescing;
// R13 unswizzled 64B rows -> 8-way conflicts; R4 B-from-global gather.
// 128x128 tile, 4 waves (2x2 of 64x64).
//   Out[m][n] = bf16( a2[m] + c2[n] - 2 * sum_k A[m][k]*Cb[n][k] )
// ---------------------------------------------------------------------------
__global__ __launch_bounds__(256, 3) void gemm_d2_fused(const u8* __restrict__ Fq,
                                                        const u8* __restrict__ Cq,
                                                        const float* __restrict__ f2,
                                                        const float* __restrict__ c2,
                                                        bf16_t* __restrict__ Dfc,
                                                        bf16_t* __restrict__ Dcc) {
    __shared__ __align__(16) u8 As[2][128 * 64];   // [panel][row*64 + swizzled]
    __shared__ __align__(16) u8 Bs[2][128 * 64];

    const int tid  = threadIdx.x;
    const int wave = tid >> 6;
    const int lane = tid & 63;

    // XCD-contiguous tile remap (T1). Dispatch order round-robins blocks
    // across the 8 XCDs (m09), so dispatch-linear id `lin`: lin&7 = XCD.
    // Give XCD x the contiguous by-range [6x, 6x+6), bx-major within it:
    // A-panel (256KB) fetched once per XCD and L2-hot for its 16 bx tiles;
    // bijective since 768 % 8 == 0 (ERRATA #11 satisfied).
    const int lin = blockIdx.y * gridDim.x + blockIdx.x;
    const int xcd = lin & 7;
    const int q_  = lin >> 3;                 // 0..95 per-XCD sequence
    const int by  = xcd * 6 + (q_ >> 4);      // 6 by-panels per XCD
    const int bxn = q_ & 15;

    const u8* A; const float* a2v; bf16_t* Out; int bm;
    if (by < B_ROWS / 128) { A = Fq; a2v = f2; Out = Dfc; bm = by * 128; }
    else { A = Cq; a2v = c2; Out = Dcc; bm = (by - B_ROWS / 128) * 128; }
    const int bn = bxn * 128;
    const int N = C_ROWS, K = D_DIM;

    const int wm = (wave >> 1) * 64;
    const int wn = (wave & 1) * 64;

    f32x4 acc[4][4] = {};

    const int c0   = wave * 2;            // staging chunks 2w, 2w+1 (16 rows)
    const int rsub = lane >> 2;           // 0..15 row within chunk
    // staging source chunk for slot (lane&3): (lane&3) ^ ((row>>1)&3)
    const int kbyt = ((lane & 3) ^ ((lane >> 3) & 3)) * 16;
    const int mrow = lane & 15;
    const int swr  = (mrow >> 1) & 3;     // read-side swizzle for this lane's row
    const int kg   = lane >> 4;           // k-group 0..3
    const int pnl  = kg >> 1;             // panel this lane reads
    const int half = kg & 1;              // 32B half within the 64B row
    const int sl0  = ((half * 2    ) ^ swr) * 16;  // swizzled slot of 1st 16B
    const int sl1  = ((half * 2 + 1) ^ swr) * 16;  // swizzled slot of 2nd 16B

    for (int k0 = 0; k0 < K; k0 += 128) {
        #pragma unroll
        for (int pn = 0; pn < 2; ++pn) {       // K-panel: k0 + pn*64 + [0,64)
            #pragma unroll
            for (int t = 0; t < 2; ++t) {
                int chunk = c0 + t;
                int row = chunk * 16 + rsub;
                const u8* gA = A  + (size_t)(bm + row) * K + (k0 + pn * 64 + kbyt);
                const u8* gB = Cq + (size_t)(bn + row) * K + (k0 + pn * 64 + kbyt);
                __builtin_amdgcn_global_load_lds(
                    (const __attribute__((address_space(1))) void*)gA,
                    (__attribute__((address_space(3))) void*)&As[pn][chunk * 1024], 16, 0, 0);
                __builtin_amdgcn_global_load_lds(
                    (const __attribute__((address_space(1))) void*)gB,
                    (__attribute__((address_space(3))) void*)&Bs[pn][chunk * 1024], 16, 0, 0);
            }
        }
        __syncthreads();

        // One K=128 step: 8 fragments x 2 ds_read_b128, 16 scaled MFMAs.
        i32x8 af[4], bf_[4];
        #pragma unroll
        for (int i = 0; i < 4; ++i) {
            int offA = (wm + i * 16 + mrow) * 64;
            int offB = (wn + i * 16 + mrow) * 64;
            i32x4 alo = *(const i32x4*)&As[pnl][offA + sl0];
            i32x4 ahi = *(const i32x4*)&As[pnl][offA + sl1];
            i32x4 blo = *(const i32x4*)&Bs[pnl][offB + sl0];
            i32x4 bhi = *(const i32x4*)&Bs[pnl][offB + sl1];
            af[i][0] = alo.x; af[i][1] = alo.y; af[i][2] = alo.z; af[i][3] = alo.w;
            af[i][4] = ahi.x; af[i][5] = ahi.y; af[i][6] = ahi.z; af[i][7] = ahi.w;
            bf_[i][0] = blo.x; bf_[i][1] = blo.y; bf_[i][2] = blo.z; bf_[i][3] = blo.w;
            bf_[i][4] = bhi.x; bf_[i][5] = bhi.y; bf_[i][6] = bhi.z; bf_[i][7] = bhi.w;
        }
        #pragma unroll
        for (int i = 0; i < 4; ++i)
            #pragma unroll
            for (int j = 0; j < 4; ++j)
                acc[i][j] = __builtin_amdgcn_mfma_scale_f32_16x16x128_f8f6f4(
                    af[i], bf_[j], acc[i][j],
                    0, 0,                 // cbsz=0 (A fp8 e4m3), blgp=0 (B fp8)
                    0, 0x7F7F7F7F,        // scale A: E8M0 1.0 in every byte
                    0, 0x7F7F7F7F);       // scale B: 1.0
        __syncthreads();
    }

    // Epilogue: d2 = a2[m] + c2[n] - 2*dot, stored bf16.
    // C/D layout shape-determined, dtype-independent (m121-128):
    // col=lane&15, row=(lane>>4)*4+reg
    const int ncol = lane & 15;
    const int r4   = (lane >> 4) * 4;
    #pragma unroll
    for (int i = 0; i < 4; ++i) {
        #pragma unroll
        for (int r = 0; r < 4; ++r) {
            int m = bm + wm + i * 16 + r4 + r;
            float am = a2v[m];
            #pragma unroll
            for (int j = 0; j < 4; ++j) {
                int n = bn + wn + j * 16 + ncol;
                Out[(size_t)m * N + n] = (bf16_t)(am + c2[n] - 2.0f * acc[i][j][r]);
            }
        }
    }
}

// ---------------------------------------------------------------------------
// select v3: bf16 distance rows, vectorized 16B loads.
// Iterative argmin w/ exclusion over Dfc row; on-demand trust from Dcc:
//   label in near3[sel]  <=>  #{ j : (Dcc[sel][j], j) <lex (Dcc[sel][label],
//   label) } < NEAREST   (stable argsort -> lexicographic order)
// Ownership: lane l, group g, sub e: n = g*512 + l*8 + e; excl bit g*8+e.
// 4 waves/block, one row per wave; one atomicAdd per block onto out.
// ---------------------------------------------------------------------------
__global__ __launch_bounds__(256) void select_kernel(const bf16_t* __restrict__ Dfc,
                                                     const bf16_t* __restrict__ Dcc,
                                                     float* __restrict__ out, int C) {
    int wave = threadIdx.x >> 6, lane = threadIdx.x & 63;
    int b = blockIdx.x * 4 + wave;
    int label = b / NUM;
    const bf16_t* row = Dfc + (size_t)b * C;

    float vals[32];
    #pragma unroll
    for (int g = 0; g < 4; ++g) {
        bf16x8 v = *(const bf16x8*)(row + g * 512 + lane * 8);
        #pragma unroll
        for (int e = 0; e < 8; ++e) {
            int n = g * 512 + lane * 8 + e;
            float f = (float)v[e];
            vals[g * 8 + e] = (n == label) ? INFINITY : f;
        }
    }

    unsigned int excl = 0;
    float min_diff = 0.0f;
    int found = 0;
    for (int it = 0; it < MAX_ITER; ++it) {
        float bestv = INFINITY; int bestidx = 0x7fffffff;
        #pragma unroll
        for (int g = 0; g < 4; ++g)
            #pragma unroll
            for (int e = 0; e < 8; ++e) {
                int bit = g * 8 + e;
                if (excl & (1u << bit)) continue;
                float v = vals[bit];
                int idx = g * 512 + lane * 8 + e;
                if (v < bestv || (v == bestv && idx < bestidx)) { bestv = v; bestidx = idx; }
            }
        for (int off = 32; off >= 1; off >>= 1) {
            float ov = __shfl_down(bestv, off); int oi = __shfl_down(bestidx, off);
            if (ov < bestv || (ov == bestv && oi < bestidx)) { bestv = ov; bestidx = oi; }
        }
        int sel = __shfl(bestidx, 0);
        float selv = __shfl(bestv, 0);

        // --- on-demand trust: count lex-smaller entries of Dcc row sel ---
        const bf16_t* crow = Dcc + (size_t)sel * C;
        float dl = (float)crow[label];          // uniform address: broadcast
        int cnt = 0;
        #pragma unroll
        for (int g = 0; g < 4; ++g) {
            bf16x8 v = *(const bf16x8*)(crow + g * 512 + lane * 8);
            #pragma unroll
            for (int e = 0; e < 8; ++e) {
                int idx = g * 512 + lane * 8 + e;
                float f = (float)v[e];
                cnt += (f < dl || (f == dl && idx < label)) ? 1 : 0;
            }
        }
        #pragma unroll
        for (int off = 32; off >= 1; off >>= 1) cnt += __shfl_down(cnt, off);
        cnt = __shfl(cnt, 0);
        bool trusted = (cnt >= NEAREST);

        if (trusted) { min_diff = sqrtf(fmaxf(selv, 0.0f)); found = 1; break; }
        if (((sel >> 3) & 63) == lane) excl |= 1u << (((sel >> 9) << 3) | (sel & 7));
    }
    __shared__ float hs[4];
    if (lane == 0) {
        float same = sqrtf(fmaxf((float)row[label], 0.0f));
        float md = found ? min_diff : 0.0f;
        hs[wave] = fmaxf(MARGIN + same - md, 0.0f);
    }
    __syncthreads();
    if (threadIdx.x == 0)
        atomicAdd(out, (hs[0] + hs[1] + hs[2] + hs[3]) * (1.0f / (float)B_ROWS));
}

// ---------------------------------------------------------------------------
extern "C" void kernel_launch(void* const* d_in, const int* in_sizes, int n_in,
                              void* d_out, int out_size, void* d_ws, size_t ws_size,
                              hipStream_t stream) {
    const float* feature = (const float*)d_in[0];  // 4096 x 2048
    const float* centers = (const float*)d_in[1];  // 2048 x 2048
    float* out = (float*)d_out;                    // scalar

    // Workspace layout (distances bf16, quantized inputs fp8)
    bf16_t* Dfc  = (bf16_t*)d_ws;                            // 4096*2048 bf16
    bf16_t* Dcc  = Dfc + (size_t)B_ROWS * C_ROWS;            // 2048*2048 bf16
    u8*     Fq   = (u8*)(Dcc + (size_t)C_ROWS * C_ROWS);     // 4096*2048 fp8
    u8*     Cq   = Fq + (size_t)B_ROWS * D_DIM;              // 2048*2048 fp8
    float*  f2   = (float*)(Cq + (size_t)C_ROWS * D_DIM);    // 4096
    float*  c2   = f2 + B_ROWS;                              // 2048

    conv_rows<<<(B_ROWS + C_ROWS) / 4, 256, 0, stream>>>(feature, centers, Fq, Cq,
                                                         f2, c2, out);

    // Both distance matrices in one dispatch: grid (16, 32+16) = 768 blocks;
    // tile ids remapped in-kernel for XCD-contiguous A-panel L2 reuse.
    gemm_d2_fused<<<dim3(C_ROWS / 128, B_ROWS / 128 + C_ROWS / 128), 256, 0, stream>>>(
        Fq, Cq, f2, c2, Dfc, Dcc);

    // select with on-demand trust (reads Dcc directly; no near3 dispatch).
    select_kernel<<<B_ROWS / 4, 256, 0, stream>>>(Dfc, Dcc, out, C_ROWS);
}